// Round 4
// baseline (438.575 us; speedup 1.0000x reference)
//
#include <hip/hip_runtime.h>
#include <hip/hip_bf16.h>

#define NN 8192
#define FIN 256
#define FOUT 64

typedef int iv4 __attribute__((ext_vector_type(4)));

// K1: Wh = H@W + bW; s = Wh.a1 + a_b; t = Wh.a2; exps + interleaved PP=(e^t, e^.01t).
__global__ __launch_bounds__(256) void k1_proj(
    const float* __restrict__ H, const float* __restrict__ W,
    const float* __restrict__ bW, const float* __restrict__ aw,
    const float* __restrict__ ab,
    float* __restrict__ Wh, float* __restrict__ s_src, float* __restrict__ t_tar,
    float* __restrict__ E1, float* __restrict__ E2, float* __restrict__ PP)
{
    __shared__ float Hs[16 * FIN];
    int tid = threadIdx.x;
    int i0 = blockIdx.x * 16;
    const float4* Hv = (const float4*)(H + (size_t)i0 * FIN);
    float4* Hsv = (float4*)Hs;
    for (int idx = tid; idx < 16 * FIN / 4; idx += 256) Hsv[idx] = Hv[idx];
    __syncthreads();
    int f = tid & 63, sub = tid >> 6;
    float a1f = aw[f], a2f = aw[64 + f];
    float b = bW[f];
    float acc0 = b, acc1 = b, acc2 = b, acc3 = b;
    for (int k = 0; k < FIN; ++k) {
        float w = W[k * FOUT + f];
        acc0 += Hs[(sub     ) * FIN + k] * w;
        acc1 += Hs[(sub +  4) * FIN + k] * w;
        acc2 += Hs[(sub +  8) * FIN + k] * w;
        acc3 += Hs[(sub + 12) * FIN + k] * w;
    }
    float accs[4] = {acc0, acc1, acc2, acc3};
    #pragma unroll
    for (int q = 0; q < 4; ++q) {
        int i = i0 + sub + 4 * q;
        float a = accs[q];
        Wh[(size_t)i * FOUT + f] = a;
        float v1 = a * a1f, v2 = a * a2f;
        #pragma unroll
        for (int o = 32; o > 0; o >>= 1) {
            v1 += __shfl_xor(v1, o);
            v2 += __shfl_xor(v2, o);
        }
        if (f == 0) {
            float s = v1 + ab[0];
            float t = v2;
            s_src[i] = s; t_tar[i] = t;
            E1[i] = __expf(s); E2[i] = __expf(0.01f * s);
            PP[2 * i]     = __expf(t);
            PP[2 * i + 1] = __expf(0.01f * t);
        }
    }
}

// K24: heterogeneous blocks.
//  b < 1024 : denom rows — streams A (268 MB) with nontemporal int4, 8 rows/block.
//             denom[i] = E1_i*Σ_{adj,cond}P1_j + E2_i*Σ_{adj,!cond}P2_j,
//             cond = (s_i+t_j>=0) <=> E1_i*P1_j >= 1.
//  b >= 1024: rank — 256 blocks × 32 nodes: rank of t_g (ties by index) and
//             k_g = #{j : t_j < -s_g}, via LDS-staged t + wave reduction.
__global__ __launch_bounds__(256) void k24(
    const int* __restrict__ A, const float* __restrict__ PP,
    const float* __restrict__ E1, const float* __restrict__ E2,
    const float* __restrict__ t_tar, const float* __restrict__ s_src,
    float* __restrict__ denom, int* __restrict__ sorted_idx, int* __restrict__ kidx)
{
    __shared__ float sh[NN];   // rank path: full t staging. denom path: sh[0..63] reduction.
    int tid = threadIdx.x;
    int b = blockIdx.x;
    if (b < 1024) {
        int i0 = b * 8;
        float e1r[8], accA[8], accB[8];
        #pragma unroll
        for (int r = 0; r < 8; ++r) { e1r[r] = E1[i0 + r]; accA[r] = 0.f; accB[r] = 0.f; }
        const float4* PPv = (const float4*)PP;
        for (int jv = tid; jv < NN / 4; jv += 256) {
            float4 ppA = PPv[2 * jv];       // P1[j],P2[j],P1[j+1],P2[j+1]
            float4 ppB = PPv[2 * jv + 1];
            #pragma unroll
            for (int r = 0; r < 8; ++r) {
                const iv4* ap = (const iv4*)(A + (size_t)(i0 + r) * NN + jv * 4);
                iv4 a4 = __builtin_nontemporal_load(ap);
                float e1 = e1r[r];
                {
                    bool c = e1 * ppA.x >= 1.0f;
                    float af = (float)a4.x;
                    accA[r] += af * (c ? ppA.x : 0.0f);
                    accB[r] += af * (c ? 0.0f : ppA.y);
                }
                {
                    bool c = e1 * ppA.z >= 1.0f;
                    float af = (float)a4.y;
                    accA[r] += af * (c ? ppA.z : 0.0f);
                    accB[r] += af * (c ? 0.0f : ppA.w);
                }
                {
                    bool c = e1 * ppB.x >= 1.0f;
                    float af = (float)a4.z;
                    accA[r] += af * (c ? ppB.x : 0.0f);
                    accB[r] += af * (c ? 0.0f : ppB.y);
                }
                {
                    bool c = e1 * ppB.z >= 1.0f;
                    float af = (float)a4.w;
                    accA[r] += af * (c ? ppB.z : 0.0f);
                    accB[r] += af * (c ? 0.0f : ppB.w);
                }
            }
        }
        #pragma unroll
        for (int r = 0; r < 8; ++r) {
            #pragma unroll
            for (int o = 32; o > 0; o >>= 1) {
                accA[r] += __shfl_xor(accA[r], o);
                accB[r] += __shfl_xor(accB[r], o);
            }
        }
        int wv = tid >> 6;
        if ((tid & 63) == 0) {
            #pragma unroll
            for (int r = 0; r < 8; ++r) {
                sh[(wv * 8 + r) * 2]     = accA[r];
                sh[(wv * 8 + r) * 2 + 1] = accB[r];
            }
        }
        __syncthreads();
        if (tid < 8) {
            float sA = sh[tid * 2]      + sh[(8 + tid) * 2]      + sh[(16 + tid) * 2]      + sh[(24 + tid) * 2];
            float sB = sh[tid * 2 + 1]  + sh[(8 + tid) * 2 + 1]  + sh[(16 + tid) * 2 + 1]  + sh[(24 + tid) * 2 + 1];
            denom[i0 + tid] = E1[i0 + tid] * sA + E2[i0 + tid] * sB;
        }
    } else {
        int rb = b - 1024;              // 0..255, 32 nodes each
        const float4* tv = (const float4*)t_tar;
        float4* shv = (float4*)sh;
        for (int idx = tid; idx < NN / 4; idx += 256) shv[idx] = tv[idx];
        __syncthreads();
        int lane = tid & 63, wv = tid >> 6;
        int g0 = rb * 32 + wv * 8;      // 8 nodes per wave
        float tj[8], thr[8];
        int rank[8], kc[8];
        #pragma unroll
        for (int q = 0; q < 8; ++q) {
            tj[q] = sh[g0 + q]; thr[q] = -s_src[g0 + q];
            rank[q] = 0; kc[q] = 0;
        }
        for (int k = lane; k < NN; k += 64) {
            float tk = sh[k];
            #pragma unroll
            for (int q = 0; q < 8; ++q) {
                int g = g0 + q;
                rank[q] += (tk < tj[q] || (tk == tj[q] && k < g)) ? 1 : 0;
                kc[q]   += (tk < thr[q]) ? 1 : 0;
            }
        }
        #pragma unroll
        for (int q = 0; q < 8; ++q) {
            #pragma unroll
            for (int o = 32; o > 0; o >>= 1) {
                rank[q] += __shfl_xor(rank[q], o);
                kc[q]   += __shfl_xor(kc[q], o);
            }
        }
        if (lane == 0) {
            #pragma unroll
            for (int q = 0; q < 8; ++q) {
                sorted_idx[rank[q]] = g0 + q;
                kidx[g0 + q] = kc[q];
            }
        }
    }
}

// K3a: per-chunk (32 m's) totals of P1*Wh and P2*Wh in sorted order. 4 chunks/block.
__global__ __launch_bounds__(256) void k3a_tots(
    const float* __restrict__ Wh, const float* __restrict__ PP,
    const int* __restrict__ sorted_idx,
    float* __restrict__ tots1, float* __restrict__ tots2)
{
    int c = blockIdx.x * 4 + (threadIdx.x >> 6);
    int f = threadIdx.x & 63;
    float t1 = 0.f, t2 = 0.f;
    int m0 = c * 32;
    #pragma unroll 8
    for (int m = m0; m < m0 + 32; ++m) {
        int sj = sorted_idx[m];
        float wh = Wh[(size_t)sj * 64 + f];
        t1 += PP[2 * sj]     * wh;
        t2 += PP[2 * sj + 1] * wh;
    }
    tots1[c * 64 + f] = t1; tots2[c * 64 + f] = t2;
}

// K3b: scan 256 chunk totals -> off2[c] = Σ_{c'<c} tots2, off1[c] = Σ_{c'>c} tots1.
// off2[256] = grand total2 (for k==NN); off1[256] = 0.
__global__ __launch_bounds__(1024) void k3b_scan(
    const float* __restrict__ tots1, const float* __restrict__ tots2,
    float* __restrict__ off1, float* __restrict__ off2)
{
    __shared__ float w1[16 * 64], w2[16 * 64];
    int tid = threadIdx.x, f = tid & 63, wv = tid >> 6;
    int c0 = wv * 16;
    float s1 = 0.f, s2 = 0.f;
    for (int c = c0; c < c0 + 16; ++c) { s1 += tots1[c * 64 + f]; s2 += tots2[c * 64 + f]; }
    w1[wv * 64 + f] = s1; w2[wv * 64 + f] = s2;
    __syncthreads();
    float o2 = 0.f;
    #pragma unroll
    for (int w = 0; w < 16; ++w) if (w < wv) o2 += w2[w * 64 + f];
    float run2 = o2;
    for (int c = c0; c < c0 + 16; ++c) { off2[c * 64 + f] = run2; run2 += tots2[c * 64 + f]; }
    if (wv == 15) off2[256 * 64 + f] = run2;
    float o1 = 0.f;
    #pragma unroll
    for (int w = 0; w < 16; ++w) if (w > wv) o1 += w1[w * 64 + f];
    float run1 = o1;
    for (int c = c0 + 15; c >= c0; --c) { off1[c * 64 + f] = run1; run1 += tots1[c * 64 + f]; }
    if (tid < 64) off1[256 * 64 + tid] = 0.f;
}

// K5: reconstruct pre2[k_i]/suf1[k_i] from chunk offsets + <=32-entry walk, then
// out[i][f] = sigmoid( (E1_i*suf + E2_i*pre) / denom[i] ).  4 nodes/block (1/wave).
__global__ __launch_bounds__(256) void k5_out(
    const float* __restrict__ Wh, const float* __restrict__ PP,
    const int* __restrict__ sorted_idx,
    const float* __restrict__ off1, const float* __restrict__ off2,
    const int* __restrict__ kidx, const float* __restrict__ E1,
    const float* __restrict__ E2, const float* __restrict__ denom,
    float* __restrict__ out)
{
    int tid = threadIdx.x;
    int f = tid & 63, wv = tid >> 6;
    int i = blockIdx.x * 4 + wv;
    int k = kidx[i];
    int c = k >> 5, r = k & 31;
    float pre = off2[c * 64 + f];
    float suf = off1[c * 64 + f];
    if (c < 256) {
        int m0 = c * 32;
        #pragma unroll 8
        for (int q = 0; q < 32; ++q) {
            int sj = sorted_idx[m0 + q];
            float wh = Wh[(size_t)sj * 64 + f];
            if (q < r) pre += PP[2 * sj + 1] * wh;
            else       suf += PP[2 * sj] * wh;
        }
    }
    float num = E1[i] * suf + E2[i] * pre;
    float x = num / denom[i];
    out[(size_t)i * 64 + f] = 1.0f / (1.0f + __expf(-x));
}

extern "C" void kernel_launch(void* const* d_in, const int* in_sizes, int n_in,
                              void* d_out, int out_size, void* d_ws, size_t ws_size,
                              hipStream_t stream) {
    const float* H  = (const float*)d_in[0];
    const int*   A  = (const int*)d_in[1];
    const float* W  = (const float*)d_in[2];
    const float* bW = (const float*)d_in[3];
    const float* aw = (const float*)d_in[4];
    const float* ab = (const float*)d_in[5];
    float* out = (float*)d_out;

    float* ws    = (float*)d_ws;
    float* Wh    = ws;                    // 524288
    float* s_src = Wh + 524288;           // 8192
    float* t_tar = s_src + 8192;          // 8192
    float* E1    = t_tar + 8192;          // 8192
    float* E2    = E1 + 8192;             // 8192
    float* PP    = E2 + 8192;             // 16384
    float* denom = PP + 16384;            // 8192
    float* tots1 = denom + 8192;          // 16384 (256*64)
    float* tots2 = tots1 + 16384;         // 16384
    float* off1  = tots2 + 16384;         // 16448 (257*64)
    float* off2  = off1 + 16448;          // 16448
    int* sorted_idx = (int*)(off2 + 16448);   // 8192 ints
    int* kidx       = sorted_idx + 8192;      // 8192 ints

    hipLaunchKernelGGL(k1_proj, dim3(512), dim3(256), 0, stream,
                       H, W, bW, aw, ab, Wh, s_src, t_tar, E1, E2, PP);
    hipLaunchKernelGGL(k24, dim3(1280), dim3(256), 0, stream,
                       A, PP, E1, E2, t_tar, s_src, denom, sorted_idx, kidx);
    hipLaunchKernelGGL(k3a_tots, dim3(64), dim3(256), 0, stream,
                       Wh, PP, sorted_idx, tots1, tots2);
    hipLaunchKernelGGL(k3b_scan, dim3(1), dim3(1024), 0, stream,
                       tots1, tots2, off1, off2);
    hipLaunchKernelGGL(k5_out, dim3(2048), dim3(256), 0, stream,
                       Wh, PP, sorted_idx, off1, off2, kidx, E1, E2, denom, out);
}